// Round 5
// baseline (78.623 us; speedup 1.0000x reference)
//
#include <hip/hip_runtime.h>
#include <stdint.h>

// Problem constants (B=2, H=8, N=2048, D=64, f32 in/out).
#define B_ 2
#define H_ 8
#define N_ 2048
#define D_ 64
#define BH_ (B_ * H_)
#define NROWS (BH_ * N_)      // 32768
#define TJ 128                // j-segment width
#define NSEG (N_ / TJ)        // 16
#define IT 128                // i-tile rows per block (4 waves x 32 rows)
#define NACT 136              // per-bh active (it,jt): sum_{it=0}^{15}(it+1)
#define NBLK (NACT * BH_)     // 2176 = 8 * 272  (XCD-swizzle friendly)
#define EPSF 8e-3f            // margin below which we re-resolve the row in f64
#define INFF __int_as_float(0x7f800000)

using u64 = unsigned long long;
using u32 = unsigned int;
typedef __attribute__((ext_vector_type(8))) short short8;   // 8 bf16
typedef __attribute__((ext_vector_type(4))) float f32x4;

// async global->LDS, 16B per lane; LDS dest = wave-uniform base + lane*16.
#define GL16(gsrc, ldst) __builtin_amdgcn_global_load_lds( \
    (const __attribute__((address_space(1))) unsigned int*)(gsrc), \
    (__attribute__((address_space(3))) unsigned int*)(ldst), 16, 0, 0)

// ---------------------------------------------------------------------------
// Prep: (a) split k into bf16 hi/lo written as PRE-SWIZZLED per-seg LDS tile
// images + ksq[r]; (b) split q into the MFMA A-fragment image so phase1 loads
// fragments with 4 coalesced dwordx4 per wave (no per-block conversion).
// qfrag layout: [bh][grp(128)][part(4: h0hi,h1hi,h0lo,h1lo)][lane(64)][16B].
// ---------------------------------------------------------------------------
__global__ __launch_bounds__(256) void prep_all(
    const float* __restrict__ q, const float* __restrict__ k,
    char* __restrict__ khi_g, char* __restrict__ klo_g,
    float* __restrict__ ksq_g, char* __restrict__ qfrag)
{
  const int blk = (int)blockIdx.x;
  if (blk < 1024) {
    // ---- k split (identical numerics to r3/r4) ----
    const int t = blk * 256 + threadIdx.x;            // NROWS*8 total
    const int r = t >> 3, kg = t & 7;
    const int jp = r & (TJ - 1);
    const float* kp = k + (size_t)r * D_ + kg * 8;
    const float4 f0 = *(const float4*)kp;
    const float4 f1 = *(const float4*)(kp + 4);
    const float vv[8] = {f0.x, f0.y, f0.z, f0.w, f1.x, f1.y, f1.z, f1.w};
    u32 hw[4], lw[4];
    float ps = 0.f;
    #pragma unroll
    for (int e = 0; e < 4; ++e) {
      const float va = vv[2 * e], vb = vv[2 * e + 1];
      ps = fmaf(va, va, ps); ps = fmaf(vb, vb, ps);
      const u32 ha = __float_as_uint(va) & 0xFFFF0000u;
      const u32 hb = __float_as_uint(vb) & 0xFFFF0000u;
      hw[e] = (ha >> 16) | hb;
      const u32 la = __float_as_uint(va - __uint_as_float(ha));
      const u32 lb = __float_as_uint(vb - __uint_as_float(hb));
      lw[e] = (la >> 16) | (lb & 0xFFFF0000u);
    }
    const u32 off = (u32)(jp * 128 + kg * 16) ^ ((u32)(jp & 7) << 4);
    const size_t tile = (size_t)(r >> 7) * 16384;     // (bh*16+jt)*16KB
    *(uint4*)(khi_g + tile + off) = make_uint4(hw[0], hw[1], hw[2], hw[3]);
    *(uint4*)(klo_g + tile + off) = make_uint4(lw[0], lw[1], lw[2], lw[3]);
    float ssum = ps;
    ssum += __shfl_xor(ssum, 1);
    ssum += __shfl_xor(ssum, 2);
    ssum += __shfl_xor(ssum, 4);
    if (kg == 0) ksq_g[r] = ssum;
  } else {
    // ---- q A-fragment split ----
    const int t2 = (blk - 1024) * 256 + threadIdx.x;  // 16*128*4*64 total
    const int l = t2 & 63;
    const int p = (t2 >> 6) & 3;
    const int grp = (t2 >> 8) & 127;
    const int bh = t2 >> 15;
    const int h = p & 1, islo = p >> 1;
    const int row = bh * N_ + grp * 16 + (l & 15);
    const float* src = q + (size_t)row * D_ + h * 32 + (l >> 4) * 8;
    const float4 f0 = *(const float4*)src;
    const float4 f1 = *(const float4*)(src + 4);
    const float vv[8] = {f0.x, f0.y, f0.z, f0.w, f1.x, f1.y, f1.z, f1.w};
    u32 wds[4];
    #pragma unroll
    for (int e = 0; e < 4; ++e) {
      const float va = vv[2 * e], vb = vv[2 * e + 1];
      const u32 ha = __float_as_uint(va) & 0xFFFF0000u;
      const u32 hb = __float_as_uint(vb) & 0xFFFF0000u;
      if (islo) {
        const u32 la = __float_as_uint(va - __uint_as_float(ha));
        const u32 lb = __float_as_uint(vb - __uint_as_float(hb));
        wds[e] = (la >> 16) | (lb & 0xFFFF0000u);
      } else {
        wds[e] = (ha >> 16) | hb;
      }
    }
    const size_t off = ((((size_t)bh * 128 + grp) * 4 + p) * 64 + l) * 16;
    *(uint4*)(qfrag + off) = make_uint4(wds[0], wds[1], wds[2], wds[3]);
  }
}

// ---------------------------------------------------------------------------
// Phase 1 (MFMA): per (row, j-segment) argmin of score = ksq_j - 2 q.k
// (qsq dropped: constant per row, cancels in both argmin and the EPSF margin).
// Block = 4 waves; i-tile = 128 rows (wave w owns 32 rows = 2 A-frag sets);
// j-seg = 128 in LDS as bf16 hi/lo (dot = hi*hi+hi*lo+lo*hi, err ~1e-4 <<
// EPSF/2). Staging via global_load_lds from prep's pre-swizzled tiles; q via
// 4 coalesced dwordx4 fragment loads per wave. Two independent 3-MFMA chains
// per s-set (4 chains/wave ILP). Float-space best/sec tracking in-loop
// (strict < keeps first index within a lane's ascending-j stream); sortable-
// key u64 pack only for the cross-lane reduce (key asc == score asc, low bits
// = j so u64-min == first-index tie-break, matching np.argmax).
// ---------------------------------------------------------------------------
__global__ __launch_bounds__(256, 4) void phase1(
    const char* __restrict__ qfrag, const char* __restrict__ khi_g,
    const char* __restrict__ klo_g, const float* __restrict__ ksq_g,
    u64* __restrict__ bestseg, u32* __restrict__ secseg,
    u32* __restrict__ count)
{
  if (blockIdx.x == 0 && threadIdx.x == 0) count[0] = 0;
  const int b = (int)blockIdx.x;
  const int orig = (b & 7) * (NBLK / 8) + (b >> 3);   // XCD swizzle (bijective)
  const int bh = orig / NACT;
  const int x = orig - bh * NACT;
  int it = 0;
  while ((it + 1) * (it + 2) / 2 <= x) ++it;          // triangular decode
  const int jt = x - it * (it + 1) / 2;
  const int i0 = it * IT, j0 = jt * TJ;
  const bool diag = (jt == it);

  __shared__ __align__(16) char lds_khi[TJ * 128];    // 16KB swizzled tile
  __shared__ __align__(16) char lds_klo[TJ * 128];    // 16KB
  __shared__ float ksq_s[TJ];

  const int tid = threadIdx.x;
  const int lane = tid & 63, w = tid >> 6;
  const int g = lane >> 4, c0 = lane & 15, s7 = lane & 7;

  // ---- k staging (async) ----
  {
    const size_t tile = ((size_t)bh * NSEG + jt) * 16384;
    const char* srcH = khi_g + tile + (size_t)(w * 4096 + lane * 16);
    const char* srcL = klo_g + tile + (size_t)(w * 4096 + lane * 16);
    char* dH = lds_khi + w * 4096 + lane * 16;
    char* dL = lds_klo + w * 4096 + lane * 16;
    #pragma unroll
    for (int rnd = 0; rnd < 4; ++rnd) {
      GL16(srcH + rnd * 1024, dH + rnd * 1024);
      GL16(srcL + rnd * 1024, dL + rnd * 1024);
    }
    if (tid < TJ) ksq_s[tid] = ksq_g[(size_t)bh * N_ + j0 + tid];
  }

  // ---- q fragments: 4 coalesced 16B loads per s-set ----
  const int iminw = i0 + w * 32;
  short8 ah[2][2], al[2][2];
  #pragma unroll
  for (int s = 0; s < 2; ++s) {
    const int grp = it * 8 + w * 2 + s;
    const char* qb =
        qfrag + ((((size_t)bh * 128 + grp) * 4) * 64 + lane) * 16;
    ah[s][0] = *(const short8*)(qb);
    ah[s][1] = *(const short8*)(qb + 1024);
    al[s][0] = *(const short8*)(qb + 2048);
    al[s][1] = *(const short8*)(qb + 3072);
  }
  __syncthreads();   // drains GL16 vmcnt too

  // ---- main loop over 16-wide j-subtiles ----
  float bf[2][4], sf[2][4];
  u32 bj[2][4];
  #pragma unroll
  for (int s = 0; s < 2; ++s)
    #pragma unroll
    for (int r2 = 0; r2 < 4; ++r2) {
      bf[s][r2] = INFF; sf[s][r2] = INFF; bj[s][r2] = 0;
    }

  auto body = [&](int js, bool dpos) {
    const int relj = js * 16 + c0;
    const u32 offA = (u32)(relj * 128 + g * 16) ^ ((u32)s7 << 4);        // h=0
    const u32 offB = (u32)(relj * 128 + (4 + g) * 16) ^ ((u32)s7 << 4);  // h=1
    const short8 kh0 = *(const short8*)(lds_khi + offA);
    const short8 kh1 = *(const short8*)(lds_khi + offB);
    const short8 kl0 = *(const short8*)(lds_klo + offA);
    const short8 kl1 = *(const short8*)(lds_klo + offB);
    const float ks = ksq_s[relj];
    const int jcol = j0 + relj;
    #pragma unroll
    for (int s = 0; s < 2; ++s) {
      if (dpos && js > 2 * w + s) continue;     // above causal range
      const bool dsub = dpos && (js == 2 * w + s);
      f32x4 aA = {0.f, 0.f, 0.f, 0.f}, aB = {0.f, 0.f, 0.f, 0.f};
      aA = __builtin_amdgcn_mfma_f32_16x16x32_bf16(ah[s][0], kh0, aA, 0, 0, 0);
      aB = __builtin_amdgcn_mfma_f32_16x16x32_bf16(ah[s][1], kh1, aB, 0, 0, 0);
      aA = __builtin_amdgcn_mfma_f32_16x16x32_bf16(ah[s][0], kl0, aA, 0, 0, 0);
      aB = __builtin_amdgcn_mfma_f32_16x16x32_bf16(ah[s][1], kl1, aB, 0, 0, 0);
      aA = __builtin_amdgcn_mfma_f32_16x16x32_bf16(al[s][0], kh0, aA, 0, 0, 0);
      aB = __builtin_amdgcn_mfma_f32_16x16x32_bf16(al[s][1], kh1, aB, 0, 0, 0);
      #pragma unroll
      for (int reg = 0; reg < 4; ++reg) {
        float score = fmaf(-2.f, aA[reg] + aB[reg], ks);
        if (dsub) {
          const int irow = iminw + s * 16 + g * 4 + reg;
          if (jcol > irow) score = INFF;
        }
        const float loser = fmaxf(bf[s][reg], score);
        sf[s][reg] = fminf(sf[s][reg], loser);
        if (score < bf[s][reg]) bj[s][reg] = (u32)jcol;
        bf[s][reg] = fminf(bf[s][reg], score);
      }
    }
  };
  if (!diag) {
    for (int js = 0; js < 8; ++js) body(js, false);
  } else {
    for (int js = 0; js <= 2 * w + 1; ++js) body(js, true);
  }

  // ---- cross-lane reduce over the 16 col-slots (same row = same g,reg) ----
  #pragma unroll
  for (int s = 0; s < 2; ++s) {
    #pragma unroll
    for (int reg = 0; reg < 4; ++reg) {
      const u32 bbits = __float_as_uint(bf[s][reg]);
      const u32 key = bbits ^ (u32)(((int)bbits >> 31) | 0x80000000);
      u64 pk = ((u64)key << 32) | bj[s][reg];
      float bv = bf[s][reg], sv = sf[s][reg];
      #pragma unroll
      for (int m = 1; m < 16; m <<= 1) {
        const u64 opk = (u64)__shfl_xor((long long)pk, m);
        const float obv = __shfl_xor(bv, m);
        const float osv = __shfl_xor(sv, m);
        const bool take = opk < pk;
        const float loser = take ? bv : obv;
        sv = fminf(fminf(sv, osv), loser);
        if (take) { pk = opk; bv = obv; }
      }
      if (c0 == 0) {
        const size_t rr = (size_t)bh * N_ + iminw + s * 16 + g * 4 + reg;
        bestseg[(size_t)jt * NROWS + rr] = pk;
        secseg[(size_t)jt * NROWS + rr] = __float_as_uint(sv);
      }
    }
  }
}

// ---------------------------------------------------------------------------
// Combine + gather fused. Block = 256 thr handles 64 rows: stage A (t<64)
// reduces the row's <=16 segment entries (u64-min keeps first index; float
// second-best recovered via inverse key transform), flags near-ties; stage B
// all 256 threads gather v rows to out (float4). Flagged rows get provisional
// output here and are overwritten by exact_gather.
// ---------------------------------------------------------------------------
__global__ __launch_bounds__(256) void combine_gather(
    const u64* __restrict__ bestseg, const u32* __restrict__ secseg,
    const float* __restrict__ v, float* __restrict__ out,
    u32* __restrict__ flaglist, u32* __restrict__ count)
{
  __shared__ u32 idx_s[64];
  const int tid = threadIdx.x;
  const int r0 = (int)blockIdx.x * 64;
  if (tid < 64) {
    const int r = r0 + tid;
    const int i = r & (N_ - 1);
    const int smax = i >> 7;
    u64 b0 = ~0ull;
    float bcur = INFF, s1 = INFF;
    int sstar = 0;
    for (int s = 0; s <= smax; ++s) {
      const u64 kk = bestseg[(size_t)s * NROWS + r];
      const u32 key = (u32)(kk >> 32);
      const u32 bits = (key & 0x80000000u) ? (key ^ 0x80000000u) : ~key;
      const float f = __uint_as_float(bits);
      if (kk < b0) { s1 = fminf(s1, bcur); b0 = kk; bcur = f; sstar = s; }
      else s1 = fminf(s1, f);
    }
    s1 = fminf(s1, __uint_as_float(secseg[(size_t)sstar * NROWS + r]));
    idx_s[tid] = (u32)(b0 & 0xFFFFu);
    if (s1 - bcur < EPSF) {            // NaN-safe: INF-INF=NaN -> false
      const u32 p = atomicAdd(count, 1u);
      flaglist[p] = (u32)r;
    }
  }
  __syncthreads();
  #pragma unroll
  for (int iter = 0; iter < 4; ++iter) {
    const int task = tid + iter * 256;
    const int rl = task >> 4, c = task & 15;
    const int r = r0 + rl;
    const u32 j = idx_s[rl];
    const int bh = r >> 11;
    const float4 val = ((const float4*)(v + ((size_t)bh * N_ + j) * D_))[c];
    ((float4*)(out + (size_t)r * D_))[c] = val;
  }
}

// ---------------------------------------------------------------------------
// Exact f64 re-resolution of near-tie rows (+ direct out write).
// ---------------------------------------------------------------------------
__global__ __launch_bounds__(256) void exact_gather(
    const float* __restrict__ q, const float* __restrict__ k,
    const float* __restrict__ v, float* __restrict__ out,
    const u32* __restrict__ flaglist, const u32* __restrict__ count)
{
  __shared__ double qd[D_];
  __shared__ double sd[256];
  __shared__ int sj[256];
  const int tid = threadIdx.x;
  const int cnt = (int)count[0];
  for (int li = blockIdx.x; li < cnt; li += (int)gridDim.x) {
    const int r = (int)flaglist[li];
    const int bh = r >> 11;
    const int i = r & (N_ - 1);
    const float* qr = q + (size_t)r * D_;
    const float* kb = k + (size_t)bh * N_ * D_;
    if (tid < D_) qd[tid] = (double)qr[tid];
    __syncthreads();
    double qsqd = 0.0;
    for (int d = 0; d < D_; ++d) qsqd = fma(qd[d], qd[d], qsqd);
    double bbest = 1e300;
    int bjj = 0;
    for (int j = tid; j <= i; j += 256) {
      const float* kr = kb + (size_t)j * D_;
      double a0 = 0, a1 = 0, s0 = 0, s1 = 0;
      for (int d = 0; d < D_; d += 2) {
        const double k0 = (double)kr[d], k1 = (double)kr[d + 1];
        a0 = fma(qd[d], k0, a0);  a1 = fma(qd[d + 1], k1, a1);
        s0 = fma(k0, k0, s0);     s1 = fma(k1, k1, s1);
      }
      const double raw = (qsqd + (s0 + s1)) - 2.0 * (a0 + a1);
      const double d2 = raw > 0.0 ? raw : 0.0;
      if (d2 < bbest) { bbest = d2; bjj = j; }   // ascending j -> first on tie
    }
    sd[tid] = bbest; sj[tid] = bjj;
    __syncthreads();
    for (int s = 128; s > 0; s >>= 1) {
      if (tid < s) {
        const double ob = sd[tid + s]; const int oj = sj[tid + s];
        if (ob < sd[tid] || (ob == sd[tid] && oj < sj[tid])) {
          sd[tid] = ob; sj[tid] = oj;
        }
      }
      __syncthreads();
    }
    const int jwin = sj[0];
    if (tid < 16) {
      const float4 val =
          ((const float4*)(v + ((size_t)bh * N_ + jwin) * D_))[tid];
      ((float4*)(out + (size_t)r * D_))[tid] = val;
    }
    __syncthreads();
  }
}

// ---------------------------------------------------------------------------
extern "C" void kernel_launch(void* const* d_in, const int* in_sizes, int n_in,
                              void* d_out, int out_size, void* d_ws,
                              size_t ws_size, hipStream_t stream) {
  const float* q = (const float*)d_in[0];
  const float* k = (const float*)d_in[1];
  const float* v = (const float*)d_in[2];
  float* out = (float*)d_out;

  // ws layout (ws_size = 256 MiB, confirmed by harness poison fills):
  // [0: count 64B][4K: flaglist 128K][256K: ksq 128K][512K: khi 4M]
  // [4.5M: klo 4M][8.5M: qfrag 16M][32M: bestseg 4M][36M: secseg 2M]
  char* ws = (char*)d_ws;
  u32* count = (u32*)ws;
  u32* flaglist = (u32*)(ws + 4096);
  float* ksq_g = (float*)(ws + 256 * 1024);
  char* khi_g = ws + 512 * 1024;
  char* klo_g = ws + 4608 * 1024;
  char* qfrag = ws + 8704 * 1024;
  u64* bestseg = (u64*)(ws + 32ull * 1024 * 1024);
  u32* secseg = (u32*)(ws + 36ull * 1024 * 1024);

  prep_all<<<3072, 256, 0, stream>>>(q, k, khi_g, klo_g, ksq_g, qfrag);
  phase1<<<NBLK, 256, 0, stream>>>(qfrag, khi_g, klo_g, ksq_g,
                                   bestseg, secseg, count);
  combine_gather<<<NROWS / 64, 256, 0, stream>>>(bestseg, secseg, v, out,
                                                 flaglist, count);
  exact_gather<<<64, 256, 0, stream>>>(q, k, v, out, flaglist, count);
}

// Round 6
// 74.856 us; speedup vs baseline: 1.0503x; 1.0503x over previous
//
#include <hip/hip_runtime.h>
#include <stdint.h>

// Problem constants (B=2, H=8, N=2048, D=64, f32 in/out).
#define B_ 2
#define H_ 8
#define N_ 2048
#define D_ 64
#define BH_ (B_ * H_)
#define NROWS (BH_ * N_)      // 32768
#define TJ 128                // j-segment width
#define NSEG (N_ / TJ)        // 16
#define IT 128                // i-tile rows per block (4 waves x 32 rows)
#define CH 4                  // j-segments per chunk (per block)
#define NCHB 40               // per-bh chunk-blocks: sum_it ceil((it+1)/4)
#define NBLK (NCHB * BH_)     // 640 = 8 * 80 (XCD-swizzle friendly)
#define NCH 4                 // max chunks per row
#define EPSF 8e-3f            // margin below which we re-resolve the row in f64
#define INFF __int_as_float(0x7f800000)

using u64 = unsigned long long;
using u32 = unsigned int;
typedef __attribute__((ext_vector_type(8))) short short8;   // 8 bf16
typedef __attribute__((ext_vector_type(4))) float f32x4;

// async global->LDS, 16B per lane; LDS dest = wave-uniform base + lane*16.
#define GL16(gsrc, ldst) __builtin_amdgcn_global_load_lds( \
    (const __attribute__((address_space(1))) unsigned int*)(gsrc), \
    (__attribute__((address_space(3))) unsigned int*)(ldst), 16, 0, 0)

// ---------------------------------------------------------------------------
// Prep: split k into bf16 hi/lo written as PRE-SWIZZLED per-seg LDS tile
// images + ksq[r]. One thread per (row, 8-elem k-group). Also zeroes count.
// ---------------------------------------------------------------------------
__global__ __launch_bounds__(256) void prep_k(
    const float* __restrict__ k, char* __restrict__ khi_g,
    char* __restrict__ klo_g, float* __restrict__ ksq_g,
    u32* __restrict__ count)
{
  if (blockIdx.x == 0 && threadIdx.x == 0) count[0] = 0;
  const int t = (int)blockIdx.x * 256 + threadIdx.x;  // NROWS*8 total
  const int r = t >> 3, kg = t & 7;
  const int jp = r & (TJ - 1);
  const float* kp = k + (size_t)r * D_ + kg * 8;
  const float4 f0 = *(const float4*)kp;
  const float4 f1 = *(const float4*)(kp + 4);
  const float vv[8] = {f0.x, f0.y, f0.z, f0.w, f1.x, f1.y, f1.z, f1.w};
  u32 hw[4], lw[4];
  float ps = 0.f;
  #pragma unroll
  for (int e = 0; e < 4; ++e) {
    const float va = vv[2 * e], vb = vv[2 * e + 1];
    ps = fmaf(va, va, ps); ps = fmaf(vb, vb, ps);
    const u32 ha = __float_as_uint(va) & 0xFFFF0000u;
    const u32 hb = __float_as_uint(vb) & 0xFFFF0000u;
    hw[e] = (ha >> 16) | hb;
    const u32 la = __float_as_uint(va - __uint_as_float(ha));
    const u32 lb = __float_as_uint(vb - __uint_as_float(hb));
    lw[e] = (la >> 16) | (lb & 0xFFFF0000u);
  }
  const u32 off = (u32)(jp * 128 + kg * 16) ^ ((u32)(jp & 7) << 4);
  const size_t tile = (size_t)(r >> 7) * 16384;       // (bh*16+jt)*16KB
  *(uint4*)(khi_g + tile + off) = make_uint4(hw[0], hw[1], hw[2], hw[3]);
  *(uint4*)(klo_g + tile + off) = make_uint4(lw[0], lw[1], lw[2], lw[3]);
  float ssum = ps;
  ssum += __shfl_xor(ssum, 1);
  ssum += __shfl_xor(ssum, 2);
  ssum += __shfl_xor(ssum, 4);
  if (kg == 0) ksq_g[r] = ssum;
}

// ---------------------------------------------------------------------------
// Phase 1 (MFMA, chunked, double-buffered): per (row, chunk of <=4 j-segs)
// argmin of score = ksq_j - 2 q.k (qsq constant per row: cancels in argmin
// and EPSF margin). Block = 4 waves, i-stripe 128 rows (wave w owns 32 =
// 2 A-frag sets). Pipeline: stage(next seg) || compute(cur seg) with one
// __syncthreads per seg (barrier drains GL16 vmcnt + joins waves).
// dot = hi*hi + hi*lo + lo*hi (split-bf16, err ~1e-4 << EPSF/2).
// q converted in-kernel (VALU work overlaps staging latency).
// Running float best/sec/bj across the whole chunk (ascending j per lane:
// strict < keeps first index); sortable-key u64 cross-lane reduce at end
// (u64-min == first-index tie-break, matching np.argmax).
// ---------------------------------------------------------------------------
__global__ __launch_bounds__(256, 2) void phase1(
    const float* __restrict__ q, const char* __restrict__ khi_g,
    const char* __restrict__ klo_g, const float* __restrict__ ksq_g,
    u64* __restrict__ bestc, u32* __restrict__ secc)
{
  const int b = (int)blockIdx.x;
  const int orig = (b & 7) * (NBLK / 8) + (b >> 3);   // XCD swizzle (bijective)
  const int bh = orig / NCHB;
  int rem = orig - bh * NCHB;
  int it = 0, nchk = 1;
  while (rem >= nchk) { rem -= nchk; ++it; nchk = (it + 4) >> 2; }
  const int c = rem;                                  // chunk index
  const int first = c * CH;
  const int last = min(first + CH - 1, it);
  const int nseg = last - first + 1;
  const int i0 = it * IT;

  __shared__ __align__(16) char lds_k[2][2][16384];   // [buf][hi/lo] 64KB
  __shared__ float ksq_s[2][TJ];

  const int tid = threadIdx.x;
  const int lane = tid & 63, w = tid >> 6;
  const int g = lane >> 4, c0 = lane & 15, s7 = lane & 7;

  auto stage = [&](int buf, int jt) {
    const size_t tile = ((size_t)bh * NSEG + jt) * 16384;
    const char* srcH = khi_g + tile + (size_t)(w * 4096 + lane * 16);
    const char* srcL = klo_g + tile + (size_t)(w * 4096 + lane * 16);
    char* dH = &lds_k[buf][0][w * 4096 + lane * 16];
    char* dL = &lds_k[buf][1][w * 4096 + lane * 16];
    #pragma unroll
    for (int rnd = 0; rnd < 4; ++rnd) {
      GL16(srcH + rnd * 1024, dH + rnd * 1024);
      GL16(srcL + rnd * 1024, dL + rnd * 1024);
    }
    if (tid < TJ) ksq_s[buf][tid] = ksq_g[(size_t)bh * N_ + jt * TJ + tid];
  };

  stage(0, first);   // issue first tile; latency hides under q-convert below

  // ---- q: 2 A-frag sets (rows iminw+s*16+c0) converted in-kernel ----
  const int iminw = i0 + w * 32;
  short8 ah[2][2], al[2][2];
  #pragma unroll
  for (int s = 0; s < 2; ++s) {
    const float* qrow =
        q + ((size_t)bh * N_ + iminw + s * 16 + c0) * D_ + g * 8;
    #pragma unroll
    for (int h = 0; h < 2; ++h) {
      const float4 f0 = *(const float4*)(qrow + h * 32);
      const float4 f1 = *(const float4*)(qrow + h * 32 + 4);
      const float vv[8] = {f0.x, f0.y, f0.z, f0.w, f1.x, f1.y, f1.z, f1.w};
      #pragma unroll
      for (int e = 0; e < 8; ++e) {
        const float v = vv[e];
        const u32 hb = __float_as_uint(v) & 0xFFFF0000u;
        ah[s][h][e] = (short)(hb >> 16);
        al[s][h][e] = (short)(__float_as_uint(v - __uint_as_float(hb)) >> 16);
      }
    }
  }
  __syncthreads();   // drains stage(0)

  // ---- running best/sec across the chunk ----
  float bf[2][4], sf[2][4];
  u32 bj[2][4];
  #pragma unroll
  for (int s = 0; s < 2; ++s)
    #pragma unroll
    for (int r2 = 0; r2 < 4; ++r2) {
      bf[s][r2] = INFF; sf[s][r2] = INFF; bj[s][r2] = 0;
    }

  for (int m = 0; m < nseg; ++m) {
    const int jt = first + m;
    if (m + 1 < nseg) stage((m + 1) & 1, jt + 1);   // prefetch next seg
    const int buf = m & 1;
    const char* baseH = lds_k[buf][0];
    const char* baseL = lds_k[buf][1];
    const float* kss = ksq_s[buf];
    const bool diag = (jt == it);
    const int j0 = jt * TJ;
    const int jsmax = diag ? (2 * w + 1) : 7;
    for (int js = 0; js <= jsmax; ++js) {
      const int relj = js * 16 + c0;
      const u32 offA = (u32)(relj * 128 + g * 16) ^ ((u32)s7 << 4);       // h0
      const u32 offB = (u32)(relj * 128 + (4 + g) * 16) ^ ((u32)s7 << 4); // h1
      const short8 kh0 = *(const short8*)(baseH + offA);
      const short8 kh1 = *(const short8*)(baseH + offB);
      const short8 kl0 = *(const short8*)(baseL + offA);
      const short8 kl1 = *(const short8*)(baseL + offB);
      const float ks = kss[relj];
      const int jcol = j0 + relj;
      #pragma unroll
      for (int s = 0; s < 2; ++s) {
        if (diag && js > 2 * w + s) continue;       // above causal range
        const bool dsub = diag && (js == 2 * w + s);
        f32x4 aA = {0.f, 0.f, 0.f, 0.f}, aB = {0.f, 0.f, 0.f, 0.f};
        aA = __builtin_amdgcn_mfma_f32_16x16x32_bf16(ah[s][0], kh0, aA, 0, 0, 0);
        aB = __builtin_amdgcn_mfma_f32_16x16x32_bf16(ah[s][1], kh1, aB, 0, 0, 0);
        aA = __builtin_amdgcn_mfma_f32_16x16x32_bf16(ah[s][0], kl0, aA, 0, 0, 0);
        aB = __builtin_amdgcn_mfma_f32_16x16x32_bf16(ah[s][1], kl1, aB, 0, 0, 0);
        aA = __builtin_amdgcn_mfma_f32_16x16x32_bf16(al[s][0], kh0, aA, 0, 0, 0);
        aB = __builtin_amdgcn_mfma_f32_16x16x32_bf16(al[s][1], kh1, aB, 0, 0, 0);
        #pragma unroll
        for (int reg = 0; reg < 4; ++reg) {
          float score = fmaf(-2.f, aA[reg] + aB[reg], ks);
          if (dsub) {
            const int irow = iminw + s * 16 + g * 4 + reg;
            if (jcol > irow) score = INFF;
          }
          const float loser = fmaxf(bf[s][reg], score);
          sf[s][reg] = fminf(sf[s][reg], loser);
          if (score < bf[s][reg]) bj[s][reg] = (u32)jcol;
          bf[s][reg] = fminf(bf[s][reg], score);
        }
      }
    }
    __syncthreads();   // joins waves + drains prefetch vmcnt
  }

  // ---- cross-lane reduce over the 16 col-slots; store one entry/row ----
  #pragma unroll
  for (int s = 0; s < 2; ++s) {
    #pragma unroll
    for (int reg = 0; reg < 4; ++reg) {
      const u32 bbits = __float_as_uint(bf[s][reg]);
      const u32 key = bbits ^ (u32)(((int)bbits >> 31) | 0x80000000);
      u64 pk = ((u64)key << 32) | bj[s][reg];
      float bv = bf[s][reg], sv = sf[s][reg];
      #pragma unroll
      for (int m = 1; m < 16; m <<= 1) {
        const u64 opk = (u64)__shfl_xor((long long)pk, m);
        const float obv = __shfl_xor(bv, m);
        const float osv = __shfl_xor(sv, m);
        const bool take = opk < pk;
        const float loser = take ? bv : obv;
        sv = fminf(fminf(sv, osv), loser);
        if (take) { pk = opk; bv = obv; }
      }
      if (c0 == 0) {
        const size_t rr = (size_t)bh * N_ + iminw + s * 16 + g * 4 + reg;
        bestc[(size_t)c * NROWS + rr] = pk;
        secc[(size_t)c * NROWS + rr] = __float_as_uint(sv);
      }
    }
  }
}

// ---------------------------------------------------------------------------
// Combine + gather fused. Block = 256 thr handles 64 rows: stage A (t<64)
// reduces the row's <=4 chunk entries (u64-min keeps first index; float
// recovered via inverse key transform), flags near-ties; stage B all 256
// threads gather v rows to out (float4). Flagged rows get provisional output
// here and are overwritten by exact_gather.
// ---------------------------------------------------------------------------
__global__ __launch_bounds__(256) void combine_gather(
    const u64* __restrict__ bestc, const u32* __restrict__ secc,
    const float* __restrict__ v, float* __restrict__ out,
    u32* __restrict__ flaglist, u32* __restrict__ count)
{
  __shared__ u32 idx_s[64];
  const int tid = threadIdx.x;
  const int r0 = (int)blockIdx.x * 64;
  if (tid < 64) {
    const int r = r0 + tid;
    const int i = r & (N_ - 1);
    const int nch = ((i >> 7) + 4) >> 2;   // chunks covering row i
    u64 b0 = ~0ull;
    float bcur = INFF, s1 = INFF;
    int cstar = 0;
    for (int c2 = 0; c2 < nch; ++c2) {
      const u64 kk = bestc[(size_t)c2 * NROWS + r];
      const u32 key = (u32)(kk >> 32);
      const u32 bits = (key & 0x80000000u) ? (key ^ 0x80000000u) : ~key;
      const float f = __uint_as_float(bits);
      if (kk < b0) { s1 = fminf(s1, bcur); b0 = kk; bcur = f; cstar = c2; }
      else s1 = fminf(s1, f);
    }
    s1 = fminf(s1, __uint_as_float(secc[(size_t)cstar * NROWS + r]));
    idx_s[tid] = (u32)(b0 & 0xFFFFu);
    if (s1 - bcur < EPSF) {            // NaN-safe: INF-INF=NaN -> false
      const u32 p = atomicAdd(count, 1u);
      flaglist[p] = (u32)r;
    }
  }
  __syncthreads();
  #pragma unroll
  for (int iter = 0; iter < 4; ++iter) {
    const int task = tid + iter * 256;
    const int rl = task >> 4, cc = task & 15;
    const int r = r0 + rl;
    const u32 j = idx_s[rl];
    const int bh = r >> 11;
    const float4 val = ((const float4*)(v + ((size_t)bh * N_ + j) * D_))[cc];
    ((float4*)(out + (size_t)r * D_))[cc] = val;
  }
}

// ---------------------------------------------------------------------------
// Exact f64 re-resolution of near-tie rows (+ direct out write).
// ---------------------------------------------------------------------------
__global__ __launch_bounds__(256) void exact_gather(
    const float* __restrict__ q, const float* __restrict__ k,
    const float* __restrict__ v, float* __restrict__ out,
    const u32* __restrict__ flaglist, const u32* __restrict__ count)
{
  __shared__ double qd[D_];
  __shared__ double sd[256];
  __shared__ int sj[256];
  const int tid = threadIdx.x;
  const int cnt = (int)count[0];
  for (int li = blockIdx.x; li < cnt; li += (int)gridDim.x) {
    const int r = (int)flaglist[li];
    const int bh = r >> 11;
    const int i = r & (N_ - 1);
    const float* qr = q + (size_t)r * D_;
    const float* kb = k + (size_t)bh * N_ * D_;
    if (tid < D_) qd[tid] = (double)qr[tid];
    __syncthreads();
    double qsqd = 0.0;
    for (int d = 0; d < D_; ++d) qsqd = fma(qd[d], qd[d], qsqd);
    double bbest = 1e300;
    int bjj = 0;
    for (int j = tid; j <= i; j += 256) {
      const float* kr = kb + (size_t)j * D_;
      double a0 = 0, a1 = 0, s0 = 0, s1 = 0;
      for (int d = 0; d < D_; d += 2) {
        const double k0 = (double)kr[d], k1 = (double)kr[d + 1];
        a0 = fma(qd[d], k0, a0);  a1 = fma(qd[d + 1], k1, a1);
        s0 = fma(k0, k0, s0);     s1 = fma(k1, k1, s1);
      }
      const double raw = (qsqd + (s0 + s1)) - 2.0 * (a0 + a1);
      const double d2 = raw > 0.0 ? raw : 0.0;
      if (d2 < bbest) { bbest = d2; bjj = j; }   // ascending j -> first on tie
    }
    sd[tid] = bbest; sj[tid] = bjj;
    __syncthreads();
    for (int s = 128; s > 0; s >>= 1) {
      if (tid < s) {
        const double ob = sd[tid + s]; const int oj = sj[tid + s];
        if (ob < sd[tid] || (ob == sd[tid] && oj < sj[tid])) {
          sd[tid] = ob; sj[tid] = oj;
        }
      }
      __syncthreads();
    }
    const int jwin = sj[0];
    if (tid < 16) {
      const float4 val =
          ((const float4*)(v + ((size_t)bh * N_ + jwin) * D_))[tid];
      ((float4*)(out + (size_t)r * D_))[tid] = val;
    }
    __syncthreads();
  }
}

// ---------------------------------------------------------------------------
extern "C" void kernel_launch(void* const* d_in, const int* in_sizes, int n_in,
                              void* d_out, int out_size, void* d_ws,
                              size_t ws_size, hipStream_t stream) {
  const float* q = (const float*)d_in[0];
  const float* k = (const float*)d_in[1];
  const float* v = (const float*)d_in[2];
  float* out = (float*)d_out;

  // ws layout (256 MiB available):
  // [0: count][4K: flaglist 128K][256K: ksq 128K][1M: khi 4M][8M: klo 4M]
  // [16M: bestc 1M][24M: secc 512K]
  char* ws = (char*)d_ws;
  u32* count = (u32*)ws;
  u32* flaglist = (u32*)(ws + 4096);
  float* ksq_g = (float*)(ws + 256 * 1024);
  char* khi_g = ws + 1ull * 1024 * 1024;
  char* klo_g = ws + 8ull * 1024 * 1024;
  u64* bestc = (u64*)(ws + 16ull * 1024 * 1024);
  u32* secc = (u32*)(ws + 24ull * 1024 * 1024);

  prep_k<<<(NROWS * 8) / 256, 256, 0, stream>>>(k, khi_g, klo_g, ksq_g, count);
  phase1<<<NBLK, 256, 0, stream>>>(q, khi_g, klo_g, ksq_g, bestc, secc);
  combine_gather<<<NROWS / 64, 256, 0, stream>>>(bestc, secc, v, out,
                                                 flaglist, count);
  exact_gather<<<64, 256, 0, stream>>>(q, k, v, out, flaglist, count);
}